// Round 5
// baseline (358.914 us; speedup 1.0000x reference)
//
#include <hip/hip_runtime.h>
#include <hip/hip_cooperative_groups.h>
#include <hip/hip_bf16.h>

namespace cg = cooperative_groups;

typedef __attribute__((ext_vector_type(8))) unsigned short u16x8;
typedef __attribute__((ext_vector_type(8))) short short8;
typedef __attribute__((ext_vector_type(4))) float floatx4;

#define BS 64
#define CIN 256
#define II 1024
#define OO 320
#define JJ 10
#define DD 32

__device__ __forceinline__ float b2f(unsigned short u) {
    union { unsigned int i; float f; } x; x.i = ((unsigned int)u) << 16; return x.f;
}
__device__ __forceinline__ unsigned short f2b(float f) {
    union { float f; unsigned int i; } x; x.f = f;
    unsigned int r = x.i + 0x7fffu + ((x.i >> 16) & 1u);
    return (unsigned short)(r >> 16);
}

// sum over the 16-lane group (lm dimension)
__device__ __forceinline__ float redlm(float v) {
    v += __shfl_xor(v, 1); v += __shfl_xor(v, 2);
    v += __shfl_xor(v, 4); v += __shfl_xor(v, 8);
    return v;
}
// sum over the 4 quads
__device__ __forceinline__ float redquad(float v) {
    v += __shfl_xor(v, 16); v += __shfl_xor(v, 32);
    return v;
}

// ---------- prep: W f32 [320][256] -> frag-linear bf16 Wl ----------
// Wl element group gid=((ks*20+mt)*4+quad)*16+lm holds 8 bf16:
//   W[o = mt*16+lm][c = ks*32 + quad*8 + j], j=0..7
__global__ __launch_bounds__(256) void k_prepW(const float* __restrict__ W,
                                               unsigned short* __restrict__ Wl) {
    int gid = blockIdx.x * 256 + threadIdx.x;      // 40 blocks -> 10240 threads
    int lm = gid & 15;
    int q  = (gid >> 4) & 3;
    int r2 = gid >> 6;                              // ks*20 + mt
    int mt = r2 % 20, ks = r2 / 20;
    const float* src = W + (size_t)(mt * 16 + lm) * CIN + ks * 32 + q * 8;
    float4 v0 = *(const float4*)src;
    float4 v1 = *(const float4*)(src + 4);
    u16x8 u;
    u[0] = f2b(v0.x); u[1] = f2b(v0.y); u[2] = f2b(v0.z); u[3] = f2b(v0.w);
    u[4] = f2b(v1.x); u[5] = f2b(v1.y); u[6] = f2b(v1.z); u[7] = f2b(v1.w);
    *(u16x8*)(Wl + (size_t)gid * 8) = u;
}

// ---------- the fused cooperative kernel ----------
// grid (4 i-chunks, 64 b) x 512 thr. Wave w owns i = ic*256 + w*32 + {lm, 16+lm}.
// acc[mt][r]: o = mt*16 + quad*4 + r  (verified 16x16x32 C layout).
__global__ __launch_bounds__(512, 2) void k_fused(const float* __restrict__ x,
                                                  const unsigned short* __restrict__ Wl,
                                                  const float* __restrict__ Wb,
                                                  float* __restrict__ psum,
                                                  float* __restrict__ out) {
    __shared__ unsigned short AsF[40960];   // 81,920 B: one 4-ks half, frag-linear
    __shared__ float ws_lds[8][OO];         // per-wave partials
    __shared__ float s_lds[OO];
    __shared__ float v_lds[OO];
    __shared__ float cf[JJ];
    __shared__ float Wb_lds[OO];

    const int ic = blockIdx.x, b = blockIdx.y;
    const int t = threadIdx.x, w = t >> 6, l = t & 63;
    const int lm = l & 15, quad = l >> 4;
    cg::grid_group grid = cg::this_grid();

    for (int u = t; u < OO; u += 512) Wb_lds[u] = Wb[u];

    // ================= GEMM phase: pred tile -> registers =================
    floatx4 accA[20] = {}, accB[20] = {};
    const float* xb = x + (size_t)b * CIN * II + ic * 256 + w * 32;

    // stage half 0 (ks 0..3)
    {
        const u16x8* src = (const u16x8*)Wl;
        u16x8* dst = (u16x8*)AsF;
        for (int u = t; u < 5120; u += 512) dst[u] = src[u];
    }
    __syncthreads();

    float rxA[2][8], rxB[2][8];
#pragma unroll
    for (int j = 0; j < 8; ++j) {                   // loads for ks=0
        size_t off = (size_t)(quad * 8 + j) * II;
        rxA[0][j] = xb[off + lm];
        rxB[0][j] = xb[off + 16 + lm];
    }

#pragma unroll
    for (int ks = 0; ks < 8; ++ks) {
        if (ks == 4) {
            __syncthreads();                        // done reading half 0
            const u16x8* src = (const u16x8*)(Wl + 4 * 20 * 4 * 16 * 8);
            u16x8* dst = (u16x8*)AsF;
            for (int u = t; u < 5120; u += 512) dst[u] = src[u];
            __syncthreads();
        }
        if (ks < 7) {
#pragma unroll
            for (int j = 0; j < 8; ++j) {           // prefetch ks+1
                size_t off = (size_t)((ks + 1) * 32 + quad * 8 + j) * II;
                rxA[(ks + 1) & 1][j] = xb[off + lm];
                rxB[(ks + 1) & 1][j] = xb[off + 16 + lm];
            }
        }
        short8 fa, fb;
#pragma unroll
        for (int j = 0; j < 8; ++j) {
            fa[j] = (short)f2b(rxA[ks & 1][j]);
            fb[j] = (short)f2b(rxB[ks & 1][j]);
        }
        const int ksl = ks & 3;
#pragma unroll
        for (int mt = 0; mt < 20; ++mt) {
            short8 af = *(const short8*)(AsF + (size_t)((((ksl * 20 + mt) * 4 + quad) * 16 + lm)) * 8);
            accA[mt] = __builtin_amdgcn_mfma_f32_16x16x32_bf16(af, fa, accA[mt], 0, 0, 0);
            accB[mt] = __builtin_amdgcn_mfma_f32_16x16x32_bf16(af, fb, accB[mt], 0, 0, 0);
        }
    }

    // add bias -> acc now holds exact pred (f32) for o=all 320, i=this lane's two cols
    __syncthreads();
#pragma unroll
    for (int mt = 0; mt < 20; ++mt)
#pragma unroll
        for (int r = 0; r < 4; ++r) {
            float bias = Wb_lds[mt * 16 + quad * 4 + r];
            accA[mt][r] += bias;
            accB[mt][r] += bias;
        }

    float* psum0 = psum;
    float* psum1 = psum + 4 * BS * OO;
    float* psum2 = psum + 2 * 4 * BS * OO;

    // ========== R0: rowsum partials (for s1 = 0.1 * rowsum) ==========
#pragma unroll
    for (int mt = 0; mt < 20; ++mt)
#pragma unroll
        for (int r = 0; r < 4; ++r) {
            float sum = redlm(accA[mt][r] + accB[mt][r]);
            if (lm == ((mt * 4 + r) & 15)) ws_lds[w][mt * 16 + quad * 4 + r] = sum;
        }
    __syncthreads();
    for (int u = t; u < OO; u += 512) {
        float bp = 0.f;
#pragma unroll
        for (int ww = 0; ww < 8; ++ww) bp += ws_lds[ww][u];
        psum0[((size_t)ic * BS + b) * OO + u] = bp;
    }
    __threadfence();
    grid.sync();

    float blogA[JJ], blogB[JJ];

    // ========== two routing passes ==========
#pragma unroll 1
    for (int pass = 0; pass < 2; ++pass) {
        const float* pin = (pass == 0) ? psum0 : psum1;
        float* pout = (pass == 0) ? psum1 : psum2;
        const float scale = (pass == 0) ? 0.1f : 1.0f;

        // consume psum -> s_lds ; squash -> v_lds
        for (int u = t; u < OO; u += 512) {
            float s = 0.f;
#pragma unroll
            for (int icc = 0; icc < 4; ++icc) s += pin[((size_t)icc * BS + b) * OO + u];
            s_lds[u] = scale * s;
        }
        __syncthreads();
        if (t < JJ) {
            float n2 = 0.f;
#pragma unroll
            for (int d = 0; d < DD; ++d) { float v = s_lds[t * DD + d]; n2 += v * v; }
            cf[t] = sqrtf(n2) / (1.0f + n2);
        }
        __syncthreads();
        for (int u = t; u < OO; u += 512) v_lds[u] = s_lds[u] * cf[u >> 5];
        __syncthreads();

        // delta + logits + softmax (per lane, two i-columns)
        float cA[JJ], cB[JJ];
        {
            float lgA[JJ], lgB[JJ];
#pragma unroll
            for (int j = 0; j < JJ; ++j) {
                float dA = 0.f, dB = 0.f;
#pragma unroll
                for (int m = 0; m < 2; ++m)
#pragma unroll
                    for (int r = 0; r < 4; ++r) {
                        float vv = v_lds[j * DD + m * 16 + quad * 4 + r];
                        dA += vv * accA[j * 2 + m][r];
                        dB += vv * accB[j * 2 + m][r];
                    }
                dA = redquad(dA);
                dB = redquad(dB);
                if (pass == 0) {
                    blogA[j] = dA; blogB[j] = dB;
                    lgA[j] = dA;   lgB[j] = dB;
                } else {
                    lgA[j] = blogA[j] + dA;
                    lgB[j] = blogB[j] + dB;
                }
            }
            float mA = lgA[0], mB = lgB[0];
#pragma unroll
            for (int j = 1; j < JJ; ++j) { mA = fmaxf(mA, lgA[j]); mB = fmaxf(mB, lgB[j]); }
            float ZA = 0.f, ZB = 0.f;
#pragma unroll
            for (int j = 0; j < JJ; ++j) {
                cA[j] = __expf(lgA[j] - mA); ZA += cA[j];
                cB[j] = __expf(lgB[j] - mB); ZB += cB[j];
            }
            float iA = 1.0f / ZA, iB = 1.0f / ZB;
#pragma unroll
            for (int j = 0; j < JJ; ++j) { cA[j] *= iA; cB[j] *= iB; }
        }

        // weighted-sum partials: s_next[o] partial over this block's i
#pragma unroll
        for (int mt = 0; mt < 20; ++mt) {
            int j = mt >> 1;
#pragma unroll
            for (int r = 0; r < 4; ++r) {
                float p = cA[j] * accA[mt][r] + cB[j] * accB[mt][r];
                p = redlm(p);
                if (lm == ((mt * 4 + r) & 15)) ws_lds[w][mt * 16 + quad * 4 + r] = p;
            }
        }
        __syncthreads();
        for (int u = t; u < OO; u += 512) {
            float bp = 0.f;
#pragma unroll
            for (int ww = 0; ww < 8; ++ww) bp += ws_lds[ww][u];
            pout[((size_t)ic * BS + b) * OO + u] = bp;
        }
        __threadfence();
        grid.sync();
    }

    // ========== final squash -> out (one i-chunk's blocks do it) ==========
    if (ic == 0) {
        for (int u = t; u < OO; u += 512) {
            float s = 0.f;
#pragma unroll
            for (int icc = 0; icc < 4; ++icc) s += psum2[((size_t)icc * BS + b) * OO + u];
            s_lds[u] = s;
        }
        __syncthreads();
        if (t < JJ) {
            float n2 = 0.f;
#pragma unroll
            for (int d = 0; d < DD; ++d) { float v = s_lds[t * DD + d]; n2 += v * v; }
            cf[t] = sqrtf(n2) / (1.0f + n2);
        }
        __syncthreads();
        for (int u = t; u < OO; u += 512) out[(size_t)b * OO + u] = s_lds[u] * cf[u >> 5];
    }
}

extern "C" void kernel_launch(void* const* d_in, const int* in_sizes, int n_in,
                              void* d_out, int out_size, void* d_ws, size_t ws_size,
                              hipStream_t stream) {
    const float* x  = (const float*)d_in[0];  // [64][256][1024] f32
    const float* W  = (const float*)d_in[1];  // [320][256] f32
    const float* Wb = (const float*)d_in[2];  // [320] f32

    char* ws = (char*)d_ws;
    unsigned short* Wl = (unsigned short*)ws;            // 163,840 B
    float* psum = (float*)(ws + 163840);                 // 3 * 4*64*320*4 = 983,040 B
    float* out = (float*)d_out;

    k_prepW<<<40, 256, 0, stream>>>(W, Wl);

    void* args[] = { (void*)&x, (void*)&Wl, (void*)&Wb, (void*)&psum, (void*)&out };
    (void)hipLaunchCooperativeKernel((void*)k_fused, dim3(4, BS), dim3(512),
                                     args, 0, stream);
}

// Round 6
// 178.334 us; speedup vs baseline: 2.0126x; 2.0126x over previous
//
#include <hip/hip_runtime.h>
#include <hip/hip_bf16.h>

typedef __attribute__((ext_vector_type(8))) unsigned short u16x8;
typedef __attribute__((ext_vector_type(4))) unsigned short u16x4;
typedef __attribute__((ext_vector_type(8))) short short8;
typedef __attribute__((ext_vector_type(4))) float floatx4;

#define BS 64
#define CIN 256
#define II 1024
#define OO 320
#define JJ 10
#define DD 32

__device__ __forceinline__ float b2f(unsigned short u) {
    union { unsigned int i; float f; } x; x.i = ((unsigned int)u) << 16; return x.f;
}
__device__ __forceinline__ unsigned short f2b(float f) {
    union { float f; unsigned int i; } x; x.f = f;
    unsigned int r = x.i + 0x7fffu + ((x.i >> 16) & 1u);
    return (unsigned short)(r >> 16);
}
// sum over the 16 lm-lanes (i dimension within a frag)
__device__ __forceinline__ float redlm(float v) {
    v += __shfl_xor(v, 1); v += __shfl_xor(v, 2);
    v += __shfl_xor(v, 4); v += __shfl_xor(v, 8);
    return v;
}

// ---------- prep: W f32 [320][256] -> chunk-major frag-linear bf16 Wl ----------
// gid = (((oc*8 + ks)*4 + mtl)*4 + quad)*16 + lm ; group holds 8 bf16:
//   W[o = oc*64 + mtl*16 + lm][c = ks*32 + quad*8 + j], j=0..7
__global__ __launch_bounds__(256) void k_prepW(const float* __restrict__ W,
                                               unsigned short* __restrict__ Wl) {
    int gid = blockIdx.x * 256 + threadIdx.x;   // 40 blocks -> 10240
    int lm = gid & 15;
    int quad = (gid >> 4) & 3;
    int mtl = (gid >> 6) & 3;
    int ks = (gid >> 8) & 7;
    int oc = gid >> 11;
    const float* src = W + (size_t)(oc * 64 + mtl * 16 + lm) * CIN + ks * 32 + quad * 8;
    float4 v0 = *(const float4*)src;
    float4 v1 = *(const float4*)(src + 4);
    u16x8 u;
    u[0] = f2b(v0.x); u[1] = f2b(v0.y); u[2] = f2b(v0.z); u[3] = f2b(v0.w);
    u[4] = f2b(v1.x); u[5] = f2b(v1.y); u[6] = f2b(v1.z); u[7] = f2b(v1.w);
    *(u16x8*)(Wl + (size_t)gid * 8) = u;
}

// ---------- K1: GEMM (direct-from-x B-frags) + fused rowsum partials ----------
// grid (8 ic, 64 b) x 512 thr (8 waves). Wave w owns i = ic*128 + w*16 + lm.
// 5 o-chunks of 64; acc lives only within a chunk (16 VGPR).
__global__ __launch_bounds__(512) void k_gemm3(const float* __restrict__ x,
                                               const unsigned short* __restrict__ Wl,
                                               const float* __restrict__ Wb,
                                               unsigned short* __restrict__ pred,
                                               float* __restrict__ psum0) {
    __shared__ unsigned short AsF[2048 * 8];   // 32 KB: one o-chunk frag-linear
    __shared__ float ws_lds[8][OO];
    __shared__ float Wb_lds[OO];

    const int ic = blockIdx.x, b = blockIdx.y;
    const int t = threadIdx.x, w = t >> 6, l = t & 63;
    const int lm = l & 15, quad = l >> 4;

    if (t < OO) Wb_lds[t] = Wb[t];

    // build B-frags from x (read-once; each wave-instr covers full 64B segments)
    const float* xb = x + (size_t)b * CIN * II + ic * 128 + w * 16 + lm;
    short8 bfrag[8];
#pragma unroll
    for (int ks = 0; ks < 8; ++ks) {
        float tmp[8];
#pragma unroll
        for (int j = 0; j < 8; ++j) tmp[j] = xb[(size_t)(ks * 32 + quad * 8 + j) * II];
        short8 f;
#pragma unroll
        for (int j = 0; j < 8; ++j) f[j] = (short)f2b(tmp[j]);
        bfrag[ks] = f;
    }

    const int ibase = ic * 128 + w * 16 + lm;
#pragma unroll 1
    for (int oc = 0; oc < 5; ++oc) {
        __syncthreads();   // prior chunk done reading AsF
        {
            const u16x8* src = (const u16x8*)Wl + oc * 2048;
            u16x8* dst = (u16x8*)AsF;
            for (int u = t; u < 2048; u += 512) dst[u] = src[u];
        }
        __syncthreads();

        floatx4 acc[4] = {};
#pragma unroll
        for (int ks = 0; ks < 8; ++ks)
#pragma unroll
            for (int mtl = 0; mtl < 4; ++mtl) {
                short8 af = *(const short8*)(AsF + (size_t)(((ks * 4 + mtl) * 4 + quad) * 16 + lm) * 8);
                acc[mtl] = __builtin_amdgcn_mfma_f32_16x16x32_bf16(af, bfrag[ks], acc[mtl], 0, 0, 0);
            }

        // epilogue: o = oc*64 + mtl*16 + quad*4 + r ; i = ibase (lm)
#pragma unroll
        for (int mtl = 0; mtl < 4; ++mtl)
#pragma unroll
            for (int r = 0; r < 4; ++r) {
                int o = oc * 64 + mtl * 16 + quad * 4 + r;
                float v = acc[mtl][r] + Wb_lds[o];
                pred[((size_t)b * OO + o) * II + ibase] = f2b(v);
                float rs = redlm(v);
                if (lm == 0) ws_lds[w][o] = rs;
            }
    }
    __syncthreads();
    for (int u = t; u < OO; u += 512) {
        float s = 0.f;
#pragma unroll
        for (int ww = 0; ww < 8; ++ww) s += ws_lds[ww][u];
        psum0[((size_t)ic * BS + b) * OO + u] = s;
    }
}

// ---------- routing pass: consume psumIn -> squash -> delta -> softmax -> wsum partials ----------
// grid (4 ic, 64 b) x 1024 thr (16 waves); ic slice = 256 i. Waves 0..9: j = w.
template <bool FIRST>
__global__ __launch_bounds__(1024) void k_routeP(const float* __restrict__ psumIn, int nslice, float scale,
                                                 const unsigned short* __restrict__ pred,
                                                 float* __restrict__ blogG,
                                                 float* __restrict__ psumOut) {
    __shared__ float s_lds[OO];
    __shared__ float v_lds[OO];
    __shared__ float cf[JJ];
    __shared__ float dbuf[JJ][256];

    const int ic = blockIdx.x, b = blockIdx.y;
    const int t = threadIdx.x, w = t >> 6, l = t & 63;

    if (t < OO) {
        float s = 0.f;
        for (int sl = 0; sl < nslice; ++sl) s += psumIn[((size_t)sl * BS + b) * OO + t];
        s_lds[t] = scale * s;
    }
    __syncthreads();
    if (t < JJ) {
        float n2 = 0.f;
#pragma unroll
        for (int d = 0; d < DD; ++d) { float v = s_lds[t * DD + d]; n2 += v * v; }
        cf[t] = sqrtf(n2) / (1.0f + n2);   // ||s|| / (1+||s||^2)
    }
    __syncthreads();
    if (t < OO) v_lds[t] = s_lds[t] * cf[t >> 5];
    __syncthreads();

    // ---- delta[j][i] = sum_d v[j,d] * pred[b][j*32+d][i], lane holds 4 i ----
    if (w < JJ) {
        float a0 = 0.f, a1 = 0.f, a2 = 0.f, a3 = 0.f;
        const unsigned short* rp = pred + ((size_t)b * OO + w * DD) * II + ic * 256 + l * 4;
#pragma unroll 8
        for (int d = 0; d < DD; ++d) {
            u16x4 u = *(const u16x4*)(rp + (size_t)d * II);
            float vv = v_lds[w * DD + d];
            a0 += vv * b2f(u[0]); a1 += vv * b2f(u[1]);
            a2 += vv * b2f(u[2]); a3 += vv * b2f(u[3]);
        }
        float4 lg;
        float* bg = blogG + ((size_t)b * JJ + w) * II + ic * 256 + l * 4;
        if (FIRST) {
            lg = make_float4(a0, a1, a2, a3);
            *(float4*)bg = lg;
        } else {
            float4 p = *(const float4*)bg;
            lg = make_float4(p.x + a0, p.y + a1, p.z + a2, p.w + a3);
        }
        *(float4*)&dbuf[w][l * 4] = lg;
    }
    __syncthreads();

    // ---- softmax over j at each i (threads 0..255) ----
    if (t < 256) {
        float lg[JJ];
#pragma unroll
        for (int j = 0; j < JJ; ++j) lg[j] = dbuf[j][t];
        float m = lg[0];
#pragma unroll
        for (int j = 1; j < JJ; ++j) m = fmaxf(m, lg[j]);
        float Z = 0.f, c[JJ];
#pragma unroll
        for (int j = 0; j < JJ; ++j) { c[j] = __expf(lg[j] - m); Z += c[j]; }
        float inv = 1.0f / Z;
#pragma unroll
        for (int j = 0; j < JJ; ++j) dbuf[j][t] = c[j] * inv;
    }
    __syncthreads();

    // ---- wsum partial: psumOut[o] = sum_{i in slice} c[j][i]*pred[b][o][i] ----
    if (w < JJ) {
        float4 c4 = *(const float4*)&dbuf[w][l * 4];
        const unsigned short* rp = pred + ((size_t)b * OO + w * DD) * II + ic * 256 + l * 4;
#pragma unroll 4
        for (int d = 0; d < DD; ++d) {
            u16x4 u = *(const u16x4*)(rp + (size_t)d * II);
            float s = c4.x * b2f(u[0]) + c4.y * b2f(u[1]) + c4.z * b2f(u[2]) + c4.w * b2f(u[3]);
#pragma unroll
            for (int off = 32; off > 0; off >>= 1) s += __shfl_down(s, off);
            if (l == 0) psumOut[((size_t)ic * BS + b) * OO + w * DD + d] = s;
        }
    }
}

// ---------- final: reduce psum2 slices, squash, write f32 out ----------
__global__ __launch_bounds__(320) void k_final2(const float* __restrict__ psum2,
                                                float* __restrict__ out) {
    __shared__ float s_lds[OO];
    __shared__ float cf[JJ];
    int b = blockIdx.x, t = threadIdx.x;
    float s = 0.f;
#pragma unroll
    for (int sl = 0; sl < 4; ++sl) s += psum2[((size_t)sl * BS + b) * OO + t];
    s_lds[t] = s;
    __syncthreads();
    if (t < JJ) {
        float n2 = 0.f;
#pragma unroll
        for (int d = 0; d < DD; ++d) { float v = s_lds[t * DD + d]; n2 += v * v; }
        cf[t] = sqrtf(n2) / (1.0f + n2);
    }
    __syncthreads();
    out[b * OO + t] = s_lds[t] * cf[t >> 5];
}

extern "C" void kernel_launch(void* const* d_in, const int* in_sizes, int n_in,
                              void* d_out, int out_size, void* d_ws, size_t ws_size,
                              hipStream_t stream) {
    const float* x  = (const float*)d_in[0];  // [64][256][1024] f32
    const float* W  = (const float*)d_in[1];  // [320][256] f32
    const float* Wb = (const float*)d_in[2];  // [320] f32

    char* ws = (char*)d_ws;
    unsigned short* pred = (unsigned short*)ws;             // 41,943,040 B
    unsigned short* Wl   = (unsigned short*)(ws + 41943040);// 163,840 B  -> 42,106,880
    float* psum0 = (float*)(ws + 42106880);                 // 655,360 B  -> 42,762,240
    float* psum1 = (float*)(ws + 42762240);                 // 327,680 B  -> 43,089,920
    float* psum2 = (float*)(ws + 43089920);                 // 327,680 B  -> 43,417,600
    float* blogG = (float*)(ws + 43417600);                 // 2,621,440 B-> 46,039,040

    k_prepW<<<40, 256, 0, stream>>>(W, Wl);
    k_gemm3<<<dim3(8, BS), 512, 0, stream>>>(x, Wl, Wb, pred, psum0);
    k_routeP<true><<<dim3(4, BS), 1024, 0, stream>>>(psum0, 8, 0.1f, pred, blogG, psum1);
    k_routeP<false><<<dim3(4, BS), 1024, 0, stream>>>(psum1, 4, 1.0f, pred, blogG, psum2);
    k_final2<<<BS, 320, 0, stream>>>(psum2, (float*)d_out);
}